// Round 7
// baseline (379.211 us; speedup 1.0000x reference)
//
#include <hip/hip_runtime.h>
#include <math.h>

#define NREG 90
#define NN 91
#define JROWS 96          // j padded to 96 (rows 91..95 zero)
#define STR 92            // A row stride in floats (368 B, 16B-aligned)
#define NPAIR 4005
#define WROWS 96          // W1T padded to 96 rows so depth-1 prefetch is guard-free
#define H1 256
#define H2 256
#define F1 128

// ---- one-shot prep: W1 [256][91] -> W1T [96][256] (rows 91..95 zero) + pair table ----
__global__ void prep(const float* __restrict__ W1, float* __restrict__ W1T,
                     int* __restrict__ ptab) {
    int t = blockIdx.x * 256 + threadIdx.x;
    if (t < WROWS * 256) {
        int k = t >> 8, h = t & 255;
        W1T[t] = (k < NN) ? W1[h * NN + k] : 0.0f;
    }
    if (t < NPAIR) {
        float disc = 32041.0f - 8.0f * (float)t;        // 179^2 - 8m
        int i = (int)floorf((179.0f - sqrtf(disc)) * 0.5f);
        if (i < 0) i = 0;
        while (i > 0 && t < i * (179 - i) / 2) --i;
        while (t >= (i + 1) * (178 - i) / 2) ++i;
        int j = i + 1 + (t - i * (179 - i) / 2);
        ptab[t] = (i << 7) | j;                          // i<=88, j<=89: 7 bits each
    }
}

__global__ __launch_bounds__(256) __attribute__((amdgpu_waves_per_eu(1, 4)))
void gcn_fused(const float* __restrict__ coh,   // [B, 4005]
               const float* __restrict__ W1T,   // [96, 256] (ws)
               const int*   __restrict__ ptab,  // [4005]    (ws)
               const float* __restrict__ W2,    // [256, 256]
               const float* __restrict__ Wo1,   // [128, 256]
               const float* __restrict__ bo1,   // [128]
               const float* __restrict__ Wo2,   // [2, 128]
               const float* __restrict__ bo2,   // [2]
               float* __restrict__ out)         // [B, 2]
{
    __shared__ __align__(16) float A[JROWS * STR];   // 35328 B
    __shared__ __align__(16) float part[4 * 64];     // 1024 B
    __shared__ __align__(16) float svec[H1];
    __shared__ __align__(16) float pooled[H2];
    __shared__ __align__(16) float fc1[F1];
    __shared__ __align__(16) float dinv[JROWS];
    // total ~39.3 KB -> 4 blocks/CU

    const int b = blockIdx.x;
    const int t = threadIdx.x;
    const float* cb = coh + (size_t)b * NPAIR;

    // ---- 1) zero A ----
    for (int m = t; m < JROWS * STR / 4; m += 256)
        ((float4*)A)[m] = make_float4(0.f, 0.f, 0.f, 0.f);
    __syncthreads();

    // ---- 2) scatter (table-driven) + supernode + identity ----
    for (int m = t; m < NPAIR; m += 256) {
        int p = ptab[m];
        int i = p >> 7, j = p & 127;
        float v = cb[m];
        A[i * STR + j] = v;
        A[j * STR + i] = v;
    }
    if (t < NN) {
        A[t * STR + t] = 1.0f;
        if (t < NREG) {
            A[NREG * STR + t] = 1.0f;
            A[t * STR + NREG] = 1.0f;
        }
    }
    __syncthreads();

    // ---- 3) degree^-1/2; pad rows dinv=0 ----
    if (t < JROWS) {
        if (t < NN) {
            const float4* row = (const float4*)&A[t * STR];
            float sx = 0.f, sy = 0.f, sz = 0.f, sw = 0.f;
            #pragma unroll
            for (int q = 0; q < STR / 4; ++q) {
                float4 v = row[q];
                sx += v.x; sy += v.y; sz += v.z; sw += v.w;
            }
            dinv[t] = 1.0f / sqrtf((sx + sy) + (sz + sw));
        } else {
            dinv[t] = 0.0f;
        }
    }
    __syncthreads();

    // ---- 4) A_hat scale ----
    for (int m = t; m < JROWS * (STR / 4); m += 256) {
        int i = m / (STR / 4);
        int c4 = (m - i * (STR / 4)) * 4;
        float di = dinv[i];
        float4 dj = *(const float4*)&dinv[c4];
        float4 v = ((float4*)A)[m];
        v.x *= di * dj.x; v.y *= di * dj.y; v.z *= di * dj.z; v.w *= di * dj.w;
        ((float4*)A)[m] = v;
    }
    __syncthreads();

    // ---- 5) main: z[j][h]=dot(Ahat[j,:],W1T[:,h]); s[h]=sum_j arow[j]*relu(z) ----
    // 16 tx (4 cols) x 16 ty (6 rows); k in steps of 4 with depth-1 W prefetch.
    const int tx = t & 15;
    const int ty = t >> 4;
    const int jb = ty * 6;
    const int wv = t >> 6;
    const float* arow = &A[NREG * STR];

    for (int q = 0; q < 4; ++q) {
        const float* Wq = W1T + q * 64 + tx * 4;
        float4 wc0 = *(const float4*)(Wq);
        float4 wc1 = *(const float4*)(Wq + 256);
        float4 wc2 = *(const float4*)(Wq + 512);
        float4 wc3 = *(const float4*)(Wq + 768);
        float acc[6][4] = {{0.f}};
        for (int k = 0; k < STR; k += 4) {               // 23 iterations
            // prefetch next 4 W rows (rows 92..95 zero-padded -> guard-free)
            const float* Wn = Wq + (size_t)(k + 4) * 256;
            float4 wn0 = *(const float4*)(Wn);
            float4 wn1 = *(const float4*)(Wn + 256);
            float4 wn2 = *(const float4*)(Wn + 512);
            float4 wn3 = *(const float4*)(Wn + 768);
            #pragma unroll
            for (int r = 0; r < 6; ++r) {
                float4 av = *(const float4*)&A[(jb + r) * STR + k];  // broadcast, 16B aligned
                acc[r][0] = fmaf(av.x, wc0.x, acc[r][0]);
                acc[r][1] = fmaf(av.x, wc0.y, acc[r][1]);
                acc[r][2] = fmaf(av.x, wc0.z, acc[r][2]);
                acc[r][3] = fmaf(av.x, wc0.w, acc[r][3]);
                acc[r][0] = fmaf(av.y, wc1.x, acc[r][0]);
                acc[r][1] = fmaf(av.y, wc1.y, acc[r][1]);
                acc[r][2] = fmaf(av.y, wc1.z, acc[r][2]);
                acc[r][3] = fmaf(av.y, wc1.w, acc[r][3]);
                acc[r][0] = fmaf(av.z, wc2.x, acc[r][0]);
                acc[r][1] = fmaf(av.z, wc2.y, acc[r][1]);
                acc[r][2] = fmaf(av.z, wc2.z, acc[r][2]);
                acc[r][3] = fmaf(av.z, wc2.w, acc[r][3]);
                acc[r][0] = fmaf(av.w, wc3.x, acc[r][0]);
                acc[r][1] = fmaf(av.w, wc3.y, acc[r][1]);
                acc[r][2] = fmaf(av.w, wc3.z, acc[r][2]);
                acc[r][3] = fmaf(av.w, wc3.w, acc[r][3]);
            }
            wc0 = wn0; wc1 = wn1; wc2 = wn2; wc3 = wn3;
        }

        // epilogue: per-thread weighted-relu partial over its 6 rows
        float sp0 = 0.f, sp1 = 0.f, sp2 = 0.f, sp3 = 0.f;
        #pragma unroll
        for (int r = 0; r < 6; ++r) {
            int j = jb + r;
            float aj = (j <= NREG) ? arow[j] : 0.0f;
            sp0 = fmaf(aj, fmaxf(acc[r][0], 0.f), sp0);
            sp1 = fmaf(aj, fmaxf(acc[r][1], 0.f), sp1);
            sp2 = fmaf(aj, fmaxf(acc[r][2], 0.f), sp2);
            sp3 = fmaf(aj, fmaxf(acc[r][3], 0.f), sp3);
        }
        sp0 += __shfl_xor(sp0, 16); sp1 += __shfl_xor(sp1, 16);
        sp2 += __shfl_xor(sp2, 16); sp3 += __shfl_xor(sp3, 16);
        sp0 += __shfl_xor(sp0, 32); sp1 += __shfl_xor(sp1, 32);
        sp2 += __shfl_xor(sp2, 32); sp3 += __shfl_xor(sp3, 32);
        if ((t & 63) < 16)
            *(float4*)&part[wv * 64 + tx * 4] = make_float4(sp0, sp1, sp2, sp3);
        __syncthreads();
        if (t < 64)
            svec[q * 64 + t] = (part[t] + part[64 + t]) + (part[128 + t] + part[192 + t]);
        __syncthreads();
    }

    // ---- 6) pooled[g] = sum_h W2[g,h] * s[h] ----
    {
        const float* w2r = W2 + t * H1;
        float p0 = 0.f, p1 = 0.f, p2 = 0.f, p3 = 0.f;
        #pragma unroll 8
        for (int qq = 0; qq < H1 / 4; ++qq) {
            float4 sv = ((const float4*)svec)[qq];
            float4 wv4 = ((const float4*)w2r)[qq];
            p0 = fmaf(sv.x, wv4.x, p0);
            p1 = fmaf(sv.y, wv4.y, p1);
            p2 = fmaf(sv.z, wv4.z, p2);
            p3 = fmaf(sv.w, wv4.w, p3);
        }
        pooled[t] = (p0 + p1) + (p2 + p3);
    }
    __syncthreads();

    // ---- 7) fc1 = relu(Wo1 @ pooled + bo1) ----
    if (t < F1) {
        const float* wo1r = Wo1 + t * H2;
        float p0 = bo1[t], p1 = 0.f, p2 = 0.f, p3 = 0.f;
        #pragma unroll 8
        for (int qq = 0; qq < H2 / 4; ++qq) {
            float4 pv = ((const float4*)pooled)[qq];
            float4 wv4 = ((const float4*)wo1r)[qq];
            p0 = fmaf(pv.x, wv4.x, p0);
            p1 = fmaf(pv.y, wv4.y, p1);
            p2 = fmaf(pv.z, wv4.z, p2);
            p3 = fmaf(pv.w, wv4.w, p3);
        }
        fc1[t] = fmaxf((p0 + p1) + (p2 + p3), 0.f);
    }
    __syncthreads();

    // ---- 8) out = Wo2 @ fc1 + bo2 ----
    if (t < 2) {
        const float* wo2r = Wo2 + t * F1;
        float p = bo2[t];
        for (int f = 0; f < F1; ++f) p = fmaf(wo2r[f], fc1[f], p);
        out[(size_t)b * 2 + t] = p;
    }
}

extern "C" void kernel_launch(void* const* d_in, const int* in_sizes, int n_in,
                              void* d_out, int out_size, void* d_ws, size_t ws_size,
                              hipStream_t stream) {
    const float* coh = (const float*)d_in[0];
    const float* W1  = (const float*)d_in[1];
    const float* W2  = (const float*)d_in[2];
    const float* Wo1 = (const float*)d_in[3];
    const float* bo1 = (const float*)d_in[4];
    const float* Wo2 = (const float*)d_in[5];
    const float* bo2 = (const float*)d_in[6];
    float* outp = (float*)d_out;

    float* W1T = (float*)d_ws;                           // 96*256*4 = 98304 B
    int*   ptab = (int*)((char*)d_ws + WROWS * 256 * 4); // 4005*4 B

    const int B = in_sizes[0] / NPAIR;   // 4096
    prep<<<96, 256, 0, stream>>>(W1, W1T, ptab);
    gcn_fused<<<B, 256, 0, stream>>>(coh, W1T, ptab, W2, Wo1, bo1, Wo2, bo2, outp);
}

// Round 8
// 266.241 us; speedup vs baseline: 1.4243x; 1.4243x over previous
//
#include <hip/hip_runtime.h>
#include <hip/hip_bf16.h>
#include <math.h>

#define NREG 90
#define NN 91
#define JROWS 96          // M and K padded to 96 (rows/cols 91..95 zero)
#define STR 100           // fp32 A LDS stride: 100%32=4 -> frag ds_reads at worst 2-way
#define NPAIR 4005
#define H1 256
#define H2 256
#define F1 128

typedef __bf16 bf16x8 __attribute__((ext_vector_type(8)));
typedef float  f32x4  __attribute__((ext_vector_type(4)));

// ---- ws layout ----
// Whi: [16 nt][3 ks][64 lane][8 e] bf16   = 24576 elems, 49152 B
// Wlo: same shape, next 49152 B
// ptab: 4005 int, at byte offset 98304      (total ~114.3 KB)

// one-shot prep: W fragments (MFMA B-operand layout, hi/lo split) + pair table
__global__ void prep(const float* __restrict__ W1, __bf16* __restrict__ Whi,
                     __bf16* __restrict__ Wlo, int* __restrict__ ptab) {
    int t = blockIdx.x * 256 + threadIdx.x;       // 0..24575
    {
        int e  = t & 7;
        int ln = (t >> 3) & 63;
        int g  = t >> 9;                          // nt*3 + ks
        int nt = g / 3;
        int ks = g - nt * 3;
        int h = nt * 16 + (ln & 15);              // B col -> output channel
        int k = ks * 32 + (ln >> 4) * 8 + e;      // B row -> k
        float v = (k < NN) ? W1[h * NN + k] : 0.0f;
        __bf16 hb = (__bf16)v;
        __bf16 lb = (__bf16)(v - (float)hb);
        Whi[t] = hb;
        Wlo[t] = lb;
    }
    if (t < NPAIR) {
        float disc = 32041.0f - 8.0f * (float)t;  // 179^2 - 8m
        int i = (int)floorf((179.0f - sqrtf(disc)) * 0.5f);
        if (i < 0) i = 0;
        while (i > 0 && t < i * (179 - i) / 2) --i;
        while (t >= (i + 1) * (178 - i) / 2) ++i;
        int j = i + 1 + (t - i * (179 - i) / 2);
        ptab[t] = (i << 7) | j;
    }
}

__global__ __launch_bounds__(256)
void gcn_fused(const float* __restrict__ coh,    // [B, 4005]
               const __bf16* __restrict__ Whi,   // [16][3][64][8] (ws)
               const __bf16* __restrict__ Wlo,   // same (ws)
               const int*   __restrict__ ptab,   // [4005] (ws)
               const float* __restrict__ W2,     // [256, 256]
               const float* __restrict__ Wo1,    // [128, 256]
               const float* __restrict__ bo1,    // [128]
               const float* __restrict__ Wo2,    // [2, 128]
               const float* __restrict__ bo2,    // [2]
               float* __restrict__ out)          // [B, 2]
{
    __shared__ __align__(16) float A[JROWS * STR];   // 38400 B
    __shared__ __align__(16) float dinv[128];
    __shared__ __align__(16) float svec[H1];
    __shared__ __align__(16) float pooled[H2];
    __shared__ __align__(16) float fc1[F1];
    // ~41.9 KB -> 3 blocks/CU (LDS)

    const int b = blockIdx.x;
    const int t = threadIdx.x;
    const float* cb = coh + (size_t)b * NPAIR;

    // ---- 1) zero A (covers all pad rows/cols) ----
    for (int m = t; m < JROWS * STR / 4; m += 256)
        ((float4*)A)[m] = make_float4(0.f, 0.f, 0.f, 0.f);
    __syncthreads();

    // ---- 2) scatter + supernode + identity ----
    for (int m = t; m < NPAIR; m += 256) {
        int p = ptab[m];
        int i = p >> 7, j = p & 127;
        float v = cb[m];
        A[i * STR + j] = v;
        A[j * STR + i] = v;
    }
    if (t < NN) {
        A[t * STR + t] = 1.0f;
        if (t < NREG) {
            A[NREG * STR + t] = 1.0f;
            A[t * STR + NREG] = 1.0f;
        }
    }
    __syncthreads();

    // ---- 3) degree^-1/2 (pad entries 0 -> rows/cols 91..99 stay zero after scale) ----
    if (t < 128) dinv[t] = 0.0f;
    if (t < NN) {
        const float4* row = (const float4*)&A[t * STR];
        float sx = 0.f, sy = 0.f, sz = 0.f, sw = 0.f;
        #pragma unroll
        for (int q = 0; q < STR / 4; ++q) {
            float4 v = row[q];
            sx += v.x; sy += v.y; sz += v.z; sw += v.w;
        }
        dinv[t] = 1.0f / sqrtf((sx + sy) + (sz + sw));
    }
    __syncthreads();

    // ---- 4) A_hat = dinv_i * A * dinv_j ----
    for (int m = t; m < JROWS * (STR / 4); m += 256) {
        int i = m / (STR / 4);
        int c4 = (m - i * (STR / 4)) * 4;
        float di = dinv[i];
        float4 dj = *(const float4*)&dinv[c4];
        float4 v = ((float4*)A)[m];
        v.x *= di * dj.x; v.y *= di * dj.y; v.z *= di * dj.z; v.w *= di * dj.w;
        ((float4*)A)[m] = v;
    }
    __syncthreads();

    // ---- 5) MFMA stage: Z = Ahat x W1T (bf16x3 split), fold relu + arow weighting ----
    // wave w owns n-tiles w*4..w*4+3 (h = ntile*16 + col). Layouts (16x16x32 bf16):
    //   A-frag: lane l, elem e -> Ahat[mtile*16 + (l&15)][ks*32 + (l>>4)*8 + e]
    //   B-frag: lane l, elem e -> W1T[ks*32 + (l>>4)*8 + e][ntile*16 + (l&15)]
    //   C/D   : lane l, reg ri -> Z[mtile*16 + (l>>4)*4 + ri][ntile*16 + (l&15)]
    {
        const int w = t >> 6, lane = t & 63;
        const int lrow = lane & 15, lkg = lane >> 4;

        bf16x8 whi_r[4][3], wlo_r[4][3];
        #pragma unroll
        for (int nt = 0; nt < 4; ++nt)
            #pragma unroll
            for (int ks = 0; ks < 3; ++ks) {
                int idx = (((w * 4 + nt) * 3 + ks) * 64 + lane) * 8;
                whi_r[nt][ks] = *(const bf16x8*)(Whi + idx);
                wlo_r[nt][ks] = *(const bf16x8*)(Wlo + idx);
            }

        float sp[4] = {0.f, 0.f, 0.f, 0.f};

        #pragma unroll 1
        for (int m = 0; m < 6; ++m) {
            // A-fragments for this m-tile: hi/lo from fp32 LDS
            bf16x8 ahi[3], alo[3];
            #pragma unroll
            for (int ks = 0; ks < 3; ++ks) {
                const float* src = &A[(m * 16 + lrow) * STR + ks * 32 + lkg * 8];
                float4 f0 = *(const float4*)src;
                float4 f1 = *(const float4*)(src + 4);
                bf16x8 hh, ll;
                hh[0] = (__bf16)f0.x; ll[0] = (__bf16)(f0.x - (float)hh[0]);
                hh[1] = (__bf16)f0.y; ll[1] = (__bf16)(f0.y - (float)hh[1]);
                hh[2] = (__bf16)f0.z; ll[2] = (__bf16)(f0.z - (float)hh[2]);
                hh[3] = (__bf16)f0.w; ll[3] = (__bf16)(f0.w - (float)hh[3]);
                hh[4] = (__bf16)f1.x; ll[4] = (__bf16)(f1.x - (float)hh[4]);
                hh[5] = (__bf16)f1.y; ll[5] = (__bf16)(f1.y - (float)hh[5]);
                hh[6] = (__bf16)f1.z; ll[6] = (__bf16)(f1.z - (float)hh[6]);
                hh[7] = (__bf16)f1.w; ll[7] = (__bf16)(f1.w - (float)hh[7]);
                ahi[ks] = hh; alo[ks] = ll;
            }
            // row-90 weights for this m-tile's 4 rows (pad j>90 naturally 0 in A)
            float aj[4];
            #pragma unroll
            for (int ri = 0; ri < 4; ++ri)
                aj[ri] = A[NREG * STR + m * 16 + lkg * 4 + ri];

            f32x4 acc[4];
            #pragma unroll
            for (int nt = 0; nt < 4; ++nt) acc[nt] = (f32x4){0.f, 0.f, 0.f, 0.f};

            #pragma unroll
            for (int ks = 0; ks < 3; ++ks) {
                #pragma unroll
                for (int nt = 0; nt < 4; ++nt) {
                    acc[nt] = __builtin_amdgcn_mfma_f32_16x16x32_bf16(ahi[ks], whi_r[nt][ks], acc[nt], 0, 0, 0);
                    acc[nt] = __builtin_amdgcn_mfma_f32_16x16x32_bf16(ahi[ks], wlo_r[nt][ks], acc[nt], 0, 0, 0);
                    acc[nt] = __builtin_amdgcn_mfma_f32_16x16x32_bf16(alo[ks], whi_r[nt][ks], acc[nt], 0, 0, 0);
                }
            }
            #pragma unroll
            for (int nt = 0; nt < 4; ++nt)
                #pragma unroll
                for (int ri = 0; ri < 4; ++ri)
                    sp[nt] = fmaf(aj[ri], fmaxf(acc[nt][ri], 0.f), sp[nt]);
        }

        // reduce the 4 row-groups (lane bits 4,5) and publish s[h]
        #pragma unroll
        for (int nt = 0; nt < 4; ++nt) {
            float s = sp[nt];
            s += __shfl_xor(s, 16);
            s += __shfl_xor(s, 32);
            if (lane < 16) svec[(w * 4 + nt) * 16 + lrow] = s;
        }
    }
    __syncthreads();

    // ---- 6) pooled[g] = sum_h W2[g,h] * s[h] ----
    {
        const float* w2r = W2 + t * H1;
        float p0 = 0.f, p1 = 0.f, p2 = 0.f, p3 = 0.f;
        #pragma unroll 8
        for (int qq = 0; qq < H1 / 4; ++qq) {
            float4 sv = ((const float4*)svec)[qq];
            float4 wv4 = ((const float4*)w2r)[qq];
            p0 = fmaf(sv.x, wv4.x, p0);
            p1 = fmaf(sv.y, wv4.y, p1);
            p2 = fmaf(sv.z, wv4.z, p2);
            p3 = fmaf(sv.w, wv4.w, p3);
        }
        pooled[t] = (p0 + p1) + (p2 + p3);
    }
    __syncthreads();

    // ---- 7) fc1 = relu(Wo1 @ pooled + bo1) ----
    if (t < F1) {
        const float* wo1r = Wo1 + t * H2;
        float p0 = bo1[t], p1 = 0.f, p2 = 0.f, p3 = 0.f;
        #pragma unroll 8
        for (int qq = 0; qq < H2 / 4; ++qq) {
            float4 pv = ((const float4*)pooled)[qq];
            float4 wv4 = ((const float4*)wo1r)[qq];
            p0 = fmaf(pv.x, wv4.x, p0);
            p1 = fmaf(pv.y, wv4.y, p1);
            p2 = fmaf(pv.z, wv4.z, p2);
            p3 = fmaf(pv.w, wv4.w, p3);
        }
        fc1[t] = fmaxf((p0 + p1) + (p2 + p3), 0.f);
    }
    __syncthreads();

    // ---- 8) out = Wo2 @ fc1 + bo2 ----
    if (t < 2) {
        const float* wo2r = Wo2 + t * F1;
        float p = bo2[t];
        for (int f = 0; f < F1; ++f) p = fmaf(wo2r[f], fc1[f], p);
        out[(size_t)b * 2 + t] = p;
    }
}

extern "C" void kernel_launch(void* const* d_in, const int* in_sizes, int n_in,
                              void* d_out, int out_size, void* d_ws, size_t ws_size,
                              hipStream_t stream) {
    const float* coh = (const float*)d_in[0];
    const float* W1  = (const float*)d_in[1];
    const float* W2  = (const float*)d_in[2];
    const float* Wo1 = (const float*)d_in[3];
    const float* bo1 = (const float*)d_in[4];
    const float* Wo2 = (const float*)d_in[5];
    const float* bo2 = (const float*)d_in[6];
    float* outp = (float*)d_out;

    __bf16* Whi = (__bf16*)d_ws;                       // 49152 B
    __bf16* Wlo = Whi + 24576;                         // 49152 B
    int*    ptab = (int*)((char*)d_ws + 98304);        // 16020 B

    const int B = in_sizes[0] / NPAIR;   // 4096
    prep<<<96, 256, 0, stream>>>(W1, Whi, Wlo, ptab);
    gcn_fused<<<B, 256, 0, stream>>>(coh, Whi, Wlo, ptab, W2, Wo1, bo1, Wo2, bo2, outp);
}

// Round 9
// 244.619 us; speedup vs baseline: 1.5502x; 1.0884x over previous
//
#include <hip/hip_runtime.h>
#include <hip/hip_bf16.h>
#include <math.h>

#define NREG 90
#define NN 91
#define JROWS 96          // M and K padded to 96 (rows/cols 91..95 zero)
#define STR 100           // A LDS stride (words): 100%32=4 -> frag reads at worst 2-way
#define NPAIR 4005
#define H1 256
#define H2 256
#define F1 128

typedef __bf16 bf16x8 __attribute__((ext_vector_type(8)));
typedef float  f32x4  __attribute__((ext_vector_type(4)));
typedef unsigned int u32x4v __attribute__((ext_vector_type(4)));

// pack fp32 -> (lo_bf16 << 16) | hi_bf16
__device__ __forceinline__ unsigned int pack_hl(float f) {
    __bf16 h = (__bf16)f;
    __bf16 l = (__bf16)(f - (float)h);
    unsigned short hb = __builtin_bit_cast(unsigned short, h);
    unsigned short lb = __builtin_bit_cast(unsigned short, l);
    return ((unsigned int)lb << 16) | (unsigned int)hb;
}

// ---- one-shot prep: W fragments (MFMA B-operand layout, hi/lo split) + pair table ----
__global__ void prep(const float* __restrict__ W1, __bf16* __restrict__ Whi,
                     __bf16* __restrict__ Wlo, int* __restrict__ ptab) {
    int t = blockIdx.x * 256 + threadIdx.x;       // 0..24575
    {
        int e  = t & 7;
        int ln = (t >> 3) & 63;
        int g  = t >> 9;                          // nt*3 + ks
        int nt = g / 3;
        int ks = g - nt * 3;
        int h = nt * 16 + (ln & 15);              // B col -> output channel
        int k = ks * 32 + (ln >> 4) * 8 + e;      // B row -> k
        float v = (k < NN) ? W1[h * NN + k] : 0.0f;
        __bf16 hb = (__bf16)v;
        __bf16 lb = (__bf16)(v - (float)hb);
        Whi[t] = hb;
        Wlo[t] = lb;
    }
    if (t < NPAIR) {
        float disc = 32041.0f - 8.0f * (float)t;  // 179^2 - 8m
        int i = (int)floorf((179.0f - sqrtf(disc)) * 0.5f);
        if (i < 0) i = 0;
        while (i > 0 && t < i * (179 - i) / 2) --i;
        while (t >= (i + 1) * (178 - i) / 2) ++i;
        int j = i + 1 + (t - i * (179 - i) / 2);
        ptab[t] = (i << 7) | j;
    }
}

__global__ __launch_bounds__(256)
void gcn_fused(const float* __restrict__ coh,    // [B, 4005]
               const __bf16* __restrict__ Whi,   // [16][3][64][8] (ws)
               const __bf16* __restrict__ Wlo,   // same (ws)
               const int*   __restrict__ ptab,   // [4005] (ws)
               const float* __restrict__ W2,     // [256, 256]
               const float* __restrict__ Wo1,    // [128, 256]
               const float* __restrict__ bo1,    // [128]
               const float* __restrict__ Wo2,    // [2, 128]
               const float* __restrict__ bo2,    // [2]
               float* __restrict__ out)          // [B, 2]
{
    // LDS budget: 38400 + 1024 + 1024 + 384 = 40832 B -> 4 blocks/CU (4*40832 <= 163840)
    __shared__ __align__(16) float A[JROWS * STR];      // 38400 B (cols 0..95 used)
    __shared__ __align__(16) float svec_fc1[H1];        // svec (ph5-6), then fc1 (ph7-8)
    __shared__ __align__(16) float pooled_dinv[H2];     // dinv (ph3-4), then pooled (ph6-7)
    __shared__ __align__(16) float arow[96];            // fp32 copy of Ahat row 90

    float* dinv   = pooled_dinv;
    float* pooled = pooled_dinv;

    const int b = blockIdx.x;
    const int t = threadIdx.x;
    const float* cb = coh + (size_t)b * NPAIR;

    // ---- 1) zero A cols 0..95 ----
    for (int m = t; m < JROWS * 24; m += 256) {
        int i = m / 24, g = m - i * 24;
        *(float4*)&A[i * STR + g * 4] = make_float4(0.f, 0.f, 0.f, 0.f);
    }
    __syncthreads();

    // ---- 2) scatter + supernode + identity ----
    for (int m = t; m < NPAIR; m += 256) {
        int p = ptab[m];
        int i = p >> 7, j = p & 127;
        float v = cb[m];
        A[i * STR + j] = v;
        A[j * STR + i] = v;
    }
    if (t < NN) {
        A[t * STR + t] = 1.0f;
        if (t < NREG) {
            A[NREG * STR + t] = 1.0f;
            A[t * STR + NREG] = 1.0f;
        }
    }
    __syncthreads();

    // ---- 3) degree^-1/2 (pad rows/cols stay 0) ----
    if (t < 256) dinv[t] = 0.0f;
    __syncthreads();
    if (t < NN) {
        const float4* row = (const float4*)&A[t * STR];
        float sx = 0.f, sy = 0.f, sz = 0.f, sw = 0.f;
        #pragma unroll
        for (int q = 0; q < 24; ++q) {
            float4 v = row[q];
            sx += v.x; sy += v.y; sz += v.z; sw += v.w;
        }
        dinv[t] = 1.0f / sqrtf((sx + sy) + (sz + sw));
    }
    __syncthreads();

    // ---- 4) A_hat = dinv_i * A * dinv_j; save fp32 row 90 into arow ----
    for (int m = t; m < JROWS * 24; m += 256) {
        int i = m / 24;
        int c4 = (m - i * 24) * 4;
        float di = dinv[i];
        float4 dj = *(const float4*)&dinv[c4];
        float4 v = *(float4*)&A[i * STR + c4];
        v.x *= di * dj.x; v.y *= di * dj.y; v.z *= di * dj.z; v.w *= di * dj.w;
        *(float4*)&A[i * STR + c4] = v;
        if (i == NREG) *(float4*)&arow[c4] = v;
    }
    __syncthreads();

    // ---- 4.5) in-place convert A fp32 -> packed (lo<<16|hi) bf16 pair ----
    for (int m = t; m < JROWS * 24; m += 256) {
        int i = m / 24;
        int c4 = (m - i * 24) * 4;
        float4 v = *(float4*)&A[i * STR + c4];
        uint4 p;
        p.x = pack_hl(v.x); p.y = pack_hl(v.y);
        p.z = pack_hl(v.z); p.w = pack_hl(v.w);
        *(uint4*)&A[i * STR + c4] = p;
    }
    __syncthreads();

    // ---- 5) MFMA stage: Z = Ahat x W1T (bf16x3 split), fold relu + arow weighting ----
    {
        const int w = t >> 6, lane = t & 63;
        const int lrow = lane & 15, lkg = lane >> 4;
        const unsigned int* Au = (const unsigned int*)A;

        bf16x8 whi_r[4][3], wlo_r[4][3];
        #pragma unroll
        for (int nt = 0; nt < 4; ++nt)
            #pragma unroll
            for (int ks = 0; ks < 3; ++ks) {
                int idx = (((w * 4 + nt) * 3 + ks) * 64 + lane) * 8;
                whi_r[nt][ks] = *(const bf16x8*)(Whi + idx);
                wlo_r[nt][ks] = *(const bf16x8*)(Wlo + idx);
            }

        float sp[4] = {0.f, 0.f, 0.f, 0.f};

        #pragma unroll 1
        for (int m = 0; m < 6; ++m) {
            bf16x8 ahi[3], alo[3];
            #pragma unroll
            for (int ks = 0; ks < 3; ++ks) {
                const uint4* src = (const uint4*)(Au + (m * 16 + lrow) * STR + ks * 32 + lkg * 8);
                uint4 a0 = src[0];
                uint4 a1 = src[1];
                u32x4v hw, lw;
                hw[0] = __builtin_amdgcn_perm(a0.y, a0.x, 0x05040100u);
                hw[1] = __builtin_amdgcn_perm(a0.w, a0.z, 0x05040100u);
                hw[2] = __builtin_amdgcn_perm(a1.y, a1.x, 0x05040100u);
                hw[3] = __builtin_amdgcn_perm(a1.w, a1.z, 0x05040100u);
                lw[0] = __builtin_amdgcn_perm(a0.y, a0.x, 0x07060302u);
                lw[1] = __builtin_amdgcn_perm(a0.w, a0.z, 0x07060302u);
                lw[2] = __builtin_amdgcn_perm(a1.y, a1.x, 0x07060302u);
                lw[3] = __builtin_amdgcn_perm(a1.w, a1.z, 0x07060302u);
                ahi[ks] = __builtin_bit_cast(bf16x8, hw);
                alo[ks] = __builtin_bit_cast(bf16x8, lw);
            }
            float aj[4];
            #pragma unroll
            for (int ri = 0; ri < 4; ++ri)
                aj[ri] = arow[m * 16 + lkg * 4 + ri];

            f32x4 acc[4];
            #pragma unroll
            for (int nt = 0; nt < 4; ++nt) acc[nt] = (f32x4){0.f, 0.f, 0.f, 0.f};

            #pragma unroll
            for (int ks = 0; ks < 3; ++ks) {
                #pragma unroll
                for (int nt = 0; nt < 4; ++nt) {
                    acc[nt] = __builtin_amdgcn_mfma_f32_16x16x32_bf16(ahi[ks], whi_r[nt][ks], acc[nt], 0, 0, 0);
                    acc[nt] = __builtin_amdgcn_mfma_f32_16x16x32_bf16(ahi[ks], wlo_r[nt][ks], acc[nt], 0, 0, 0);
                    acc[nt] = __builtin_amdgcn_mfma_f32_16x16x32_bf16(alo[ks], whi_r[nt][ks], acc[nt], 0, 0, 0);
                }
            }
            #pragma unroll
            for (int nt = 0; nt < 4; ++nt)
                #pragma unroll
                for (int ri = 0; ri < 4; ++ri)
                    sp[nt] = fmaf(aj[ri], fmaxf(acc[nt][ri], 0.f), sp[nt]);
        }

        __syncthreads();   // svec_fc1 free (nothing pending) -- cheap, keeps write ordering clear
        #pragma unroll
        for (int nt = 0; nt < 4; ++nt) {
            float s = sp[nt];
            s += __shfl_xor(s, 16);
            s += __shfl_xor(s, 32);
            if (lane < 16) svec_fc1[(w * 4 + nt) * 16 + lrow] = s;
        }
    }
    __syncthreads();

    // ---- 6) pooled[g] = sum_h W2[g,h] * s[h] ----
    {
        const float* w2r = W2 + t * H1;
        float p0 = 0.f, p1 = 0.f, p2 = 0.f, p3 = 0.f;
        #pragma unroll 8
        for (int qq = 0; qq < H1 / 4; ++qq) {
            float4 sv = ((const float4*)svec_fc1)[qq];
            float4 wv4 = *(const float4*)&w2r[qq * 4];
            p0 = fmaf(sv.x, wv4.x, p0);
            p1 = fmaf(sv.y, wv4.y, p1);
            p2 = fmaf(sv.z, wv4.z, p2);
            p3 = fmaf(sv.w, wv4.w, p3);
        }
        float pr = (p0 + p1) + (p2 + p3);
        __syncthreads();          // all svec reads done before pooled overwrites dinv slot
        pooled[t] = pr;
    }
    __syncthreads();

    // ---- 7) fc1 = relu(Wo1 @ pooled + bo1), into svec_fc1 ----
    {
        float fr = 0.f;
        if (t < F1) {
            const float* wo1r = Wo1 + t * H2;
            float p0 = bo1[t], p1 = 0.f, p2 = 0.f, p3 = 0.f;
            #pragma unroll 8
            for (int qq = 0; qq < H2 / 4; ++qq) {
                float4 pv = ((const float4*)pooled)[qq];
                float4 wv4 = *(const float4*)&wo1r[qq * 4];
                p0 = fmaf(pv.x, wv4.x, p0);
                p1 = fmaf(pv.y, wv4.y, p1);
                p2 = fmaf(pv.z, wv4.z, p2);
                p3 = fmaf(pv.w, wv4.w, p3);
            }
            fr = fmaxf((p0 + p1) + (p2 + p3), 0.f);
        }
        __syncthreads();          // svec reads in this phase... (none) / ordering
        if (t < F1) svec_fc1[t] = fr;
    }
    __syncthreads();

    // ---- 8) out = Wo2 @ fc1 + bo2 (wave-parallel) ----
    if (t < 64) {
        int o = t & 1;
        int f0 = t >> 1;                  // f = f0 + 32*s
        const float* wo2r = Wo2 + o * F1;
        float p = 0.f;
        #pragma unroll
        for (int s = 0; s < 4; ++s)
            p = fmaf(wo2r[f0 + 32 * s], svec_fc1[f0 + 32 * s], p);
        p += __shfl_xor(p, 2);
        p += __shfl_xor(p, 4);
        p += __shfl_xor(p, 8);
        p += __shfl_xor(p, 16);
        p += __shfl_xor(p, 32);
        if (t < 2) out[(size_t)b * 2 + t] = p + bo2[t];
    }
}

extern "C" void kernel_launch(void* const* d_in, const int* in_sizes, int n_in,
                              void* d_out, int out_size, void* d_ws, size_t ws_size,
                              hipStream_t stream) {
    const float* coh = (const float*)d_in[0];
    const float* W1  = (const float*)d_in[1];
    const float* W2  = (const float*)d_in[2];
    const float* Wo1 = (const float*)d_in[3];
    const float* bo1 = (const float*)d_in[4];
    const float* Wo2 = (const float*)d_in[5];
    const float* bo2 = (const float*)d_in[6];
    float* outp = (float*)d_out;

    __bf16* Whi = (__bf16*)d_ws;                       // 49152 B
    __bf16* Wlo = Whi + 24576;                         // 49152 B
    int*    ptab = (int*)((char*)d_ws + 98304);        // 16020 B

    const int B = in_sizes[0] / NPAIR;   // 4096
    prep<<<96, 256, 0, stream>>>(W1, Whi, Wlo, ptab);
    gcn_fused<<<B, 256, 0, stream>>>(coh, Whi, Wlo, ptab, W2, Wo1, bo1, Wo2, bo2, outp);
}